// Round 1
// baseline (206.126 us; speedup 1.0000x reference)
//
#include <hip/hip_runtime.h>

#define N_COLS 24576
#define KSEL 64
#define NBINS 2048
#define NSUB 4
#define CAP 4096
#define TPB 1024
#define F4_PER_THREAD 6   // 24576 / 4 / 1024

__device__ __forceinline__ unsigned toSortable(float x) {
    unsigned u = __float_as_uint(x);
    return (u & 0x80000000u) ? ~u : (u | 0x80000000u);
}
__device__ __forceinline__ float fromSortable(unsigned s) {
    unsigned u = (s & 0x80000000u) ? (s & 0x7FFFFFFFu) : ~s;
    return __uint_as_float(u);
}

extern "C" __global__ void __launch_bounds__(TPB, 8)
topk_relu_kernel(const float* __restrict__ x, float* __restrict__ out) {
    __shared__ unsigned hist[NSUB][NBINS];
    __shared__ unsigned cand_s[CAP];
    __shared__ unsigned short cand_i[CAP];
    __shared__ int cand_cnt;
    __shared__ int sh_b1, sh_g;

    const int tid = threadIdx.x;
    const int row = blockIdx.x;
    const float4* __restrict__ xr = (const float4*)(x + (size_t)row * N_COLS);
    float4* __restrict__ outr = (float4*)(out + (size_t)row * N_COLS);

    // zero LDS histograms + counter
    #pragma unroll
    for (int i = 0; i < (NSUB * NBINS) / TPB; ++i)
        ((unsigned*)hist)[tid + i * TPB] = 0u;
    if (tid == 0) cand_cnt = 0;
    __syncthreads();

    unsigned* myh = hist[(tid >> 6) & (NSUB - 1)];

    // ---- pass 1: histogram top-11 bits of sortable keys ----
    #pragma unroll
    for (int j = 0; j < F4_PER_THREAD; ++j) {
        int f = j * TPB + tid;
        float4 v = xr[f];
        atomicAdd(&myh[toSortable(v.x) >> 21], 1u);
        atomicAdd(&myh[toSortable(v.y) >> 21], 1u);
        atomicAdd(&myh[toSortable(v.z) >> 21], 1u);
        atomicAdd(&myh[toSortable(v.w) >> 21], 1u);
    }
    __syncthreads();

    // ---- find threshold bin b1 and g = count strictly above it (wave 0) ----
    if (tid < 64) {
        unsigned running = 0;
        for (int c = NBINS / 64 - 1; c >= 0; --c) {
            int bin = c * 64 + tid;
            unsigned cnt = hist[0][bin] + hist[1][bin] + hist[2][bin] + hist[3][bin];
            unsigned incl = cnt;
            #pragma unroll
            for (int d = 1; d < 64; d <<= 1) {
                unsigned o = __shfl_up(incl, d, 64);
                if (tid >= d) incl += o;
            }
            unsigned total = __shfl(incl, 63, 64);
            unsigned gt = running + (total - incl);   // # elements in bins strictly > bin
            bool cond = (gt < KSEL) && (gt + cnt >= KSEL);
            unsigned long long m = __ballot(cond);
            if (m != 0ULL) {
                if (cond) { sh_b1 = bin; sh_g = (int)gt; }
                break;
            }
            running += total;
        }
    }
    __syncthreads();

    const int b1 = sh_b1;
    const int g  = sh_g;

    // ---- pass 2: write output (relu / 0), gather boundary-bin candidates ----
    #pragma unroll
    for (int j = 0; j < F4_PER_THREAD; ++j) {
        int f = j * TPB + tid;
        float4 v = xr[f];
        float4 o;

        #define PROC(comp, e)                                                     \
        {                                                                         \
            unsigned s = toSortable(v.comp);                                      \
            int b = (int)(s >> 21);                                               \
            float r = 0.0f;                                                       \
            if (b > b1) {                                                         \
                r = v.comp > 0.0f ? v.comp : 0.0f;                                \
            } else if (b == b1) {                                                 \
                int p = atomicAdd(&cand_cnt, 1);                                  \
                if (p < CAP) {                                                    \
                    cand_s[p] = s;                                                \
                    cand_i[p] = (unsigned short)(f * 4 + e);                      \
                }                                                                 \
            }                                                                     \
            o.comp = r;                                                           \
        }

        PROC(x, 0)
        PROC(y, 1)
        PROC(z, 2)
        PROC(w, 3)
        #undef PROC

        outr[f] = o;
    }
    __syncthreads();   // drains stores (vmcnt) + candidate list complete

    // ---- exact rank-select among candidates, scatter selected relu values ----
    int C = cand_cnt;
    if (C > CAP) C = CAP;
    const int k1 = KSEL - g;   // how many to take from bin b1
    for (int i = tid; i < C; i += TPB) {
        unsigned si = cand_s[i];
        unsigned ii = cand_i[i];
        unsigned long long key_i =
            ((unsigned long long)si << 15) | (unsigned long long)(24575 - (int)ii);
        int rank = 0;
        for (int j = 0; j < C; ++j) {
            unsigned long long key_j =
                ((unsigned long long)cand_s[j] << 15) |
                (unsigned long long)(24575 - (int)cand_i[j]);
            rank += (key_j > key_i) ? 1 : 0;
        }
        if (rank < k1) {
            float vv = fromSortable(si);
            out[(size_t)row * N_COLS + ii] = vv > 0.0f ? vv : 0.0f;
        }
    }
}

extern "C" void kernel_launch(void* const* d_in, const int* in_sizes, int n_in,
                              void* d_out, int out_size, void* d_ws, size_t ws_size,
                              hipStream_t stream) {
    const float* x = (const float*)d_in[0];
    float* out = (float*)d_out;
    const int rows = in_sizes[0] / N_COLS;
    topk_relu_kernel<<<rows, TPB, 0, stream>>>(x, out);
}